// Round 12
// baseline (4093.389 us; speedup 1.0000x reference)
//
#include <hip/hip_runtime.h>

// Problem constants (DeepCAD_1958505087412)
#define BB   8
#define NN   512      // nodes == timesteps
#define NDIM 128
#define HDIM 256      // GNN out dim == LSTM hidden
#define TT   512

__device__ __forceinline__ float sigmoidf_(float x) { return 1.0f / (1.0f + __expf(-x)); }
__device__ __forceinline__ float tanhf_(float x) { float e = __expf(2.0f * x); return 1.0f - 2.0f / (e + 1.0f); }

typedef _Float16 half2v __attribute__((ext_vector_type(2)));
typedef unsigned int uint4v __attribute__((ext_vector_type(4)));
typedef short bf16x8 __attribute__((ext_vector_type(8)));
typedef float f32x4 __attribute__((ext_vector_type(4)));
__device__ __forceinline__ float fdot2_(unsigned int w, unsigned int h, float acc) {
    return __builtin_amdgcn_fdot2(__builtin_bit_cast(half2v, w),
                                  __builtin_bit_cast(half2v, h), acc, false);
}
__device__ __forceinline__ unsigned short f2bf_(float x) {
    unsigned int u = __builtin_bit_cast(unsigned int, x);
    return (unsigned short)((u + 0x7FFFu + ((u >> 16) & 1u)) >> 16);   // RNE
}
__device__ __forceinline__ unsigned short f2h_(float x) {
    _Float16 h = (_Float16)x;
    return *(unsigned short*)&h;
}

// ---------------------------------------------------------------------------
// fp32 Y = X @ W^T + bias (optional ReLU) — small head layer-2 GEMMs.
// ---------------------------------------------------------------------------
template<int RELU>
__global__ __launch_bounds__(256) void gemm_nt(const float* __restrict__ X,
    const float* __restrict__ W, const float* __restrict__ bias,
    float* __restrict__ Y, int M, int K, int Nn)
{
    __shared__ float Xs[16][68];
    __shared__ float Ws[16][68];
    const int tid = threadIdx.x;
    const int m0 = blockIdx.y << 6;
    const int n0 = blockIdx.x << 6;
    const int lr = tid >> 2;
    const int lc = (tid & 3) << 2;
    const int tm = (tid >> 4) << 2;
    const int tn = (tid & 15) << 2;

    float acc[4][4] = {{0.f,0.f,0.f,0.f},{0.f,0.f,0.f,0.f},{0.f,0.f,0.f,0.f},{0.f,0.f,0.f,0.f}};

    const float* Xp = X + (size_t)(m0 + lr) * K + lc;
    const bool wok = (n0 + lr) < Nn;
    const float* Wp = wok ? (W + (size_t)(n0 + lr) * K + lc) : W;

    for (int k0 = 0; k0 < K; k0 += 16) {
        float4 xv = *(const float4*)(Xp + k0);
        float4 wv = *(const float4*)(Wp + k0);
        if (!wok) wv = make_float4(0.f, 0.f, 0.f, 0.f);
        __syncthreads();
        Xs[lc+0][lr]=xv.x; Xs[lc+1][lr]=xv.y; Xs[lc+2][lr]=xv.z; Xs[lc+3][lr]=xv.w;
        Ws[lc+0][lr]=wv.x; Ws[lc+1][lr]=wv.y; Ws[lc+2][lr]=wv.z; Ws[lc+3][lr]=wv.w;
        __syncthreads();
        #pragma unroll
        for (int kk = 0; kk < 16; ++kk) {
            const float4 a = *(const float4*)(&Xs[kk][tm]);
            const float4 b = *(const float4*)(&Ws[kk][tn]);
            acc[0][0] += a.x*b.x; acc[0][1] += a.x*b.y; acc[0][2] += a.x*b.z; acc[0][3] += a.x*b.w;
            acc[1][0] += a.y*b.x; acc[1][1] += a.y*b.y; acc[1][2] += a.y*b.z; acc[1][3] += a.y*b.w;
            acc[2][0] += a.z*b.x; acc[2][1] += a.z*b.y; acc[2][2] += a.z*b.z; acc[2][3] += a.z*b.w;
            acc[3][0] += a.w*b.x; acc[3][1] += a.w*b.y; acc[3][2] += a.w*b.z; acc[3][3] += a.w*b.w;
        }
    }
    const int nc = n0 + tn;
    if (nc >= Nn) return;
    float4 bv = make_float4(0.f, 0.f, 0.f, 0.f);
    if (bias) bv = *(const float4*)(bias + nc);
    #pragma unroll
    for (int i = 0; i < 4; ++i) {
        float4 o;
        o.x = acc[i][0] + bv.x; o.y = acc[i][1] + bv.y;
        o.z = acc[i][2] + bv.z; o.w = acc[i][3] + bv.w;
        if (RELU) { o.x=fmaxf(o.x,0.f); o.y=fmaxf(o.y,0.f); o.z=fmaxf(o.z,0.f); o.w=fmaxf(o.w,0.f); }
        *(float4*)(Y + (size_t)(m0 + tm + i) * Nn + nc) = o;
    }
}

// ---------------------------------------------------------------------------
// bf16 MFMA Y = X @ W^T + bias (optional ReLU). Verified r10/r11.
// ---------------------------------------------------------------------------
template<int RELU>
__global__ __launch_bounds__(256) void gemm_nt_mfma(
    const unsigned short* __restrict__ X, const unsigned short* __restrict__ W,
    const float* __restrict__ bias, float* __restrict__ Y, int K, int Nn)
{
    __shared__ unsigned short As[128][56];
    __shared__ unsigned short Bs[128][56];
    const int tid = threadIdx.x;
    const int m0 = blockIdx.y << 7;
    const int n0 = blockIdx.x << 7;
    const int wid = tid >> 6, lane = tid & 63;
    const int wm = (wid >> 1) << 6;
    const int wn = (wid & 1) << 6;
    const int sr = tid >> 2;
    const int sc = (tid & 3) << 3;

    f32x4 acc[4][4] = {};

    const int fr = lane & 15;
    const int kg = (lane >> 4) << 3;

    for (int k0 = 0; k0 < K; k0 += 32) {
        uint4 a0 = *(const uint4*)(X + (size_t)(m0 + sr) * K + k0 + sc);
        uint4 a1 = *(const uint4*)(X + (size_t)(m0 + sr + 64) * K + k0 + sc);
        uint4 b0 = *(const uint4*)(W + (size_t)(n0 + sr) * K + k0 + sc);
        uint4 b1 = *(const uint4*)(W + (size_t)(n0 + sr + 64) * K + k0 + sc);
        __syncthreads();
        *(uint4*)&As[sr][sc] = a0; *(uint4*)&As[sr + 64][sc] = a1;
        *(uint4*)&Bs[sr][sc] = b0; *(uint4*)&Bs[sr + 64][sc] = b1;
        __syncthreads();
        bf16x8 af[4], bf[4];
        #pragma unroll
        for (int i = 0; i < 4; ++i) {
            af[i] = *(const bf16x8*)&As[wm + i * 16 + fr][kg];
            bf[i] = *(const bf16x8*)&Bs[wn + i * 16 + fr][kg];
        }
        #pragma unroll
        for (int i = 0; i < 4; ++i)
            #pragma unroll
            for (int j = 0; j < 4; ++j)
                acc[i][j] = __builtin_amdgcn_mfma_f32_16x16x32_bf16(af[i], bf[j], acc[i][j], 0, 0, 0);
    }

    const int cr = (lane >> 4) << 2;
    const int cc = lane & 15;
    #pragma unroll
    for (int i = 0; i < 4; ++i) {
        #pragma unroll
        for (int j = 0; j < 4; ++j) {
            const int col = n0 + wn + j * 16 + cc;
            const float bv = bias ? bias[col] : 0.f;
            #pragma unroll
            for (int r = 0; r < 4; ++r) {
                const int row = m0 + wm + i * 16 + cr + r;
                float v = acc[i][j][r] + bv;
                if (RELU) v = fmaxf(v, 0.f);
                Y[(size_t)row * Nn + col] = v;
            }
        }
    }
}

// ---------------------------------------------------------------------------
// Batched Y[b] = (A[b] @ H[b]) * mask[b,:,None], optional ReLU (fp32).
// ---------------------------------------------------------------------------
template<int RELU>
__global__ __launch_bounds__(256) void gemm_nn_mask(const float* __restrict__ A,
    const float* __restrict__ Hm, const float* __restrict__ mask,
    float* __restrict__ Y, int M, int K, int Nn)
{
    const int b = blockIdx.z;
    A  += (size_t)b * M * K;
    Hm += (size_t)b * K * Nn;
    Y  += (size_t)b * M * Nn;
    __shared__ float As[16][68];
    __shared__ float Hs[16][68];
    const int tid = threadIdx.x;
    const int m0 = blockIdx.y << 6;
    const int n0 = blockIdx.x << 6;
    const int lr = tid >> 2;
    const int lc = (tid & 3) << 2;
    const int hr = tid >> 4;
    const int hc = (tid & 15) << 2;
    const int tm = (tid >> 4) << 2;
    const int tn = (tid & 15) << 2;

    float acc[4][4] = {{0.f,0.f,0.f,0.f},{0.f,0.f,0.f,0.f},{0.f,0.f,0.f,0.f},{0.f,0.f,0.f,0.f}};

    for (int k0 = 0; k0 < K; k0 += 16) {
        float4 av = *(const float4*)(A + (size_t)(m0 + lr) * K + k0 + lc);
        float4 hv = *(const float4*)(Hm + (size_t)(k0 + hr) * Nn + n0 + hc);
        __syncthreads();
        As[lc+0][lr]=av.x; As[lc+1][lr]=av.y; As[lc+2][lr]=av.z; As[lc+3][lr]=av.w;
        *(float4*)(&Hs[hr][hc]) = hv;
        __syncthreads();
        #pragma unroll
        for (int kk = 0; kk < 16; ++kk) {
            const float4 a = *(const float4*)(&As[kk][tm]);
            const float4 h = *(const float4*)(&Hs[kk][tn]);
            acc[0][0] += a.x*h.x; acc[0][1] += a.x*h.y; acc[0][2] += a.x*h.z; acc[0][3] += a.x*h.w;
            acc[1][0] += a.y*h.x; acc[1][1] += a.y*h.y; acc[1][2] += a.y*h.z; acc[1][3] += a.y*h.w;
            acc[2][0] += a.z*h.x; acc[2][1] += a.z*h.y; acc[2][2] += a.z*h.z; acc[2][3] += a.z*h.w;
            acc[3][0] += a.w*h.x; acc[3][1] += a.w*h.y; acc[3][2] += a.w*h.z; acc[3][3] += a.w*h.w;
        }
    }
    #pragma unroll
    for (int i = 0; i < 4; ++i) {
        const float mk = mask[b * M + m0 + tm + i];
        float4 o;
        o.x = acc[i][0]*mk; o.y = acc[i][1]*mk; o.z = acc[i][2]*mk; o.w = acc[i][3]*mk;
        if (RELU) { o.x=fmaxf(o.x,0.f); o.y=fmaxf(o.y,0.f); o.z=fmaxf(o.z,0.f); o.w=fmaxf(o.w,0.f); }
        *(float4*)(Y + (size_t)(m0 + tm + i) * Nn + n0 + tn) = o;
    }
}

// ---------------------------------------------------------------------------
__global__ __launch_bounds__(256) void attn_sisj(const float* __restrict__ h,
    const float* __restrict__ aw, const float* __restrict__ ab,
    float* __restrict__ si, float* __restrict__ sj)
{
    const int lane = threadIdx.x & 63;
    const int row  = (blockIdx.x << 2) + (threadIdx.x >> 6);
    const float4 hv = ((const float4*)(h + (size_t)row * HDIM))[lane];
    const float4 a1 = ((const float4*)aw)[lane];
    const float4 a2 = ((const float4*)(aw + HDIM))[lane];
    float s1 = hv.x*a1.x + hv.y*a1.y + hv.z*a1.z + hv.w*a1.w;
    float s2 = hv.x*a2.x + hv.y*a2.y + hv.z*a2.z + hv.w*a2.w;
    #pragma unroll
    for (int off = 32; off > 0; off >>= 1) {
        s1 += __shfl_down(s1, off);
        s2 += __shfl_down(s2, off);
    }
    if (lane == 0) { si[row] = s1 + ab[0]; sj[row] = s2; }
}

// ---------------------------------------------------------------------------
__global__ __launch_bounds__(512) void attn_score(const float* __restrict__ si,
    const float* __restrict__ sj, const float* __restrict__ adj,
    const float* __restrict__ mask, float* __restrict__ watt)
{
    const int bi = blockIdx.x;
    const int b  = bi >> 9;
    const int j  = threadIdx.x;
    const float s0 = si[bi];
    const float mi = mask[bi];
    float s = sigmoidf_(s0 + sj[(b << 9) + j]) * adj[(size_t)bi * NN + j] * mi * mask[(b << 9) + j];
    float t = s;
    #pragma unroll
    for (int off = 32; off > 0; off >>= 1) t += __shfl_down(t, off);
    __shared__ float red[8];
    const int lane = j & 63, wv = j >> 6;
    if (lane == 0) red[wv] = t;
    __syncthreads();
    if (j == 0) {
        float tot = 0.f;
        #pragma unroll
        for (int w = 0; w < 8; ++w) tot += red[w];
        red[0] = 1.0f / (tot + 1e-8f);
    }
    __syncthreads();
    watt[(size_t)bi * NN + j] = s * red[0];
}

// ---------------------------------------------------------------------------
__global__ __launch_bounds__(256) void pack_f16(const float* __restrict__ src,
    unsigned int* __restrict__ dst, int n)
{
    int i = blockIdx.x * 256 + threadIdx.x;
    if (i < n) {
        float2 v = ((const float2*)src)[i];
        dst[i] = (unsigned int)f2h_(v.x) | ((unsigned int)f2h_(v.y) << 16);
    }
}

// ---------------------------------------------------------------------------
__global__ __launch_bounds__(256) void pack3_bf16(
    const float* __restrict__ s0, unsigned short* __restrict__ d0, int n0,
    const float* __restrict__ s1, unsigned short* __restrict__ d1, int n1,
    const float* __restrict__ s2, unsigned short* __restrict__ d2, int n2)
{
    int i = (blockIdx.x * 256 + threadIdx.x) * 4;
    const float* s; unsigned short* d; int l;
    if (i < n0) { s = s0; d = d0; l = i; }
    else if (i < n0 + n1) { s = s1; d = d1; l = i - n0; }
    else if (i < n0 + n1 + n2) { s = s2; d = d2; l = i - n0 - n1; }
    else return;
    float4 v = *(const float4*)(s + l);
    ushort4 o;
    o.x = f2bf_(v.x); o.y = f2bf_(v.y); o.z = f2bf_(v.z); o.w = f2bf_(v.w);
    *(ushort4*)(d + l) = o;
}

// ---------------------------------------------------------------------------
__global__ __launch_bounds__(256) void zero_ws(unsigned int* __restrict__ p, int n)
{
    for (int i = threadIdx.x + blockIdx.x * 256; i < n; i += 256 * gridDim.x) p[i] = 0u;
}

// ---------------------------------------------------------------------------
// Two-block-per-chain LSTM scan. r5-r9 established the single-CU floor:
// ~2.0 us/step = per-CU L2-return-path limit for the 384 KB/step weight
// stream. Fix: split each chain across 2 CUs (32 blocks = 16 chains x 2
// slices; blockIdx = slice*16+chain puts both slices of a chain on the SAME
// XCD under round-robin dispatch -> flag exchange through shared L2).
// Block owns 128 hidden units = 512 gate rows (1 row/thread, 512 threads).
// Per row (256 f16 = 32 uint4): 16 uint4 in LDS (128 KB, lane-contiguous,
// conflict-free), 16 uint4 named+pinned (64 VGPR; demand ~100 fits every
// budget). Per-step h exchange: 128 h as packed f16 (64 u32) through a
// double-buffered global buffer + per-slice monotonic release/acquire flags
// (protocol functionally proven in r2). 4 barriers/step, 2-way fan-in.
//   hb: u32[2][16][2][64]   fl: int[16][2] (MUST be zeroed before launch)
// ---------------------------------------------------------------------------
__global__ __launch_bounds__(512) __attribute__((amdgpu_waves_per_eu(2, 2)))
void lstm_scan8(
    const float* __restrict__ pre_f, const float* __restrict__ pre_b,
    const unsigned int* __restrict__ w16_f, const unsigned int* __restrict__ w16_b,
    float* __restrict__ out, unsigned int* __restrict__ hb, int* __restrict__ fl)
{
    __shared__ uint4v lw4[16 * 512];        // 128 KB: k=0..127 of each row
    __shared__ float g_s[512];              // 2 KB: gate pre-activations
    __shared__ unsigned int h2[128];        // 512 B: packed-f16 h (256 units)

    const int chain = blockIdx.x & 15;
    const int sl    = blockIdx.x >> 4;      // slice 0/1
    const int batch = chain >> 1;
    const int dir   = chain & 1;
    const float* pre = dir ? pre_b : pre_f;
    const unsigned int* w = dir ? w16_b : w16_f;
    const int t0   = threadIdx.x;           // 0..511
    const int gate = t0 >> 7;                // 0..3
    const int uoff = t0 & 127;               // unit within slice
    const int grow = gate * 256 + sl * 128 + uoff;  // row in whh (1024x256)

    const uint4v* wr = (const uint4v*)(w + (size_t)grow * 128);

    // k=0..127 -> LDS, lane-contiguous (conflict-free ds_read_b128)
    #pragma unroll
    for (int i = 0; i < 16; ++i) lw4[i * 512 + t0] = wr[i];

    // k=128..255 -> 16 named uint4 registers, pinned each iteration
#define WD(i) uint4v W##i = wr[i];
    WD(16) WD(17) WD(18) WD(19) WD(20) WD(21) WD(22) WD(23)
    WD(24) WD(25) WD(26) WD(27) WD(28) WD(29) WD(30) WD(31)
#undef WD
#define PIN_ALL \
    { \
        asm volatile("" : "+v"(W16)); asm volatile("" : "+v"(W17)); \
        asm volatile("" : "+v"(W18)); asm volatile("" : "+v"(W19)); \
        asm volatile("" : "+v"(W20)); asm volatile("" : "+v"(W21)); \
        asm volatile("" : "+v"(W22)); asm volatile("" : "+v"(W23)); \
        asm volatile("" : "+v"(W24)); asm volatile("" : "+v"(W25)); \
        asm volatile("" : "+v"(W26)); asm volatile("" : "+v"(W27)); \
        asm volatile("" : "+v"(W28)); asm volatile("" : "+v"(W29)); \
        asm volatile("" : "+v"(W30)); asm volatile("" : "+v"(W31)); \
    }
    PIN_ALL

    if (t0 < 128) h2[t0] = 0u;
    float c0 = 0.f, c1 = 0.f;

    int* myflag = fl + chain * 2 + sl;
    int* pflag  = fl + chain * 2 + (sl ^ 1);
    unsigned int* hb_c = hb + chain * 128;   // [2 phases of 16*128 u32 stride]

    const int tt0 = dir ? (TT - 1) : 0;
    const long pstep = dir ? -1024 : 1024;
    const long ostep = dir ? -512 : 512;
    const float* pp = pre + ((size_t)batch * TT + tt0) * 1024 + grow;
    float* op = out + ((size_t)batch * TT + tt0) * 512 + dir * 256 + sl * 128 + 2 * t0; // t0<64
    float pv = *pp; pp += pstep;
    __syncthreads();

    for (int t = 0; t < TT; ++t) {
        PIN_ALL

        float pv_n = 0.f;
        if (t + 1 < TT) pv_n = *pp;
        pp += pstep;

        // ---- matvec: 32 fdot2 quads (16 LDS + 16 reg) ----
        float a0 = 0.f, a1 = 0.f, a2 = 0.f, a3 = 0.f;
        const uint4v* h4 = (const uint4v*)h2;
        #pragma unroll
        for (int i = 0; i < 16; ++i) {
            const uint4v wv = lw4[i * 512 + t0];
            const uint4v hv = h4[i];
            a0 = fdot2_(wv.x, hv.x, a0); a1 = fdot2_(wv.y, hv.y, a1);
            a2 = fdot2_(wv.z, hv.z, a2); a3 = fdot2_(wv.w, hv.w, a3);
        }
#define DOT(i) { const uint4v hv = h4[i]; \
        a0 = fdot2_(W##i.x, hv.x, a0); a1 = fdot2_(W##i.y, hv.y, a1); \
        a2 = fdot2_(W##i.z, hv.z, a2); a3 = fdot2_(W##i.w, hv.w, a3); }
        DOT(16) DOT(17) DOT(18) DOT(19) DOT(20) DOT(21) DOT(22) DOT(23)
        DOT(24) DOT(25) DOT(26) DOT(27) DOT(28) DOT(29) DOT(30) DOT(31)
#undef DOT
        g_s[t0] = (a0 + a1) + (a2 + a3) + pv;
        __syncthreads();

        // ---- pointwise: thread l < 64 handles units 2l, 2l+1 of this slice --
        if (t0 < 64) {
            const int u2 = 2 * t0;
            const float ia = sigmoidf_(g_s[u2]),       ib = sigmoidf_(g_s[u2 + 1]);
            const float fa = sigmoidf_(g_s[128 + u2]), fb = sigmoidf_(g_s[128 + u2 + 1]);
            const float ga = tanhf_(g_s[256 + u2]),    gb = tanhf_(g_s[256 + u2 + 1]);
            const float oa = sigmoidf_(g_s[384 + u2]), ob = sigmoidf_(g_s[384 + u2 + 1]);
            c0 = fa * c0 + ia * ga;
            c1 = fb * c1 + ib * gb;
            const float h0 = oa * tanhf_(c0);
            const float h1 = ob * tanhf_(c1);
            *(float2*)op = make_float2(h0, h1);
            op += ostep;
            const unsigned int packed = (unsigned int)f2h_(h0) | ((unsigned int)f2h_(h1) << 16);
            h2[sl * 64 + t0] = packed;
            if (t + 1 < TT)
                __hip_atomic_store(&hb_c[(size_t)((t + 1) & 1) * 2048 + sl * 64 + t0],
                                   packed, __ATOMIC_RELAXED, __HIP_MEMORY_SCOPE_AGENT);
        }
        __syncthreads();                    // h stores drained (vmcnt) + h2 own half

        if (t + 1 < TT) {
            if (t0 == 0)
                __hip_atomic_store(myflag, t + 1, __ATOMIC_RELEASE, __HIP_MEMORY_SCOPE_AGENT);
            if (t0 == 64) {
                while (__hip_atomic_load(pflag, __ATOMIC_ACQUIRE,
                                         __HIP_MEMORY_SCOPE_AGENT) < t + 1) { }
            }
            __syncthreads();                // poll complete
            if (t0 < 64) {
                h2[(sl ^ 1) * 64 + t0] =
                    __hip_atomic_load(&hb_c[(size_t)((t + 1) & 1) * 2048 + (sl ^ 1) * 64 + t0],
                                      __ATOMIC_RELAXED, __HIP_MEMORY_SCOPE_AGENT);
            }
            __syncthreads();                // h2 complete for next matvec
        }
        pv = pv_n;
    }
#undef PIN_ALL
}

// ---------------------------------------------------------------------------

extern "C" void kernel_launch(void* const* d_in, const int* in_sizes, int n_in,
                              void* d_out, int out_size, void* d_ws, size_t ws_size,
                              hipStream_t stream)
{
    const float* nf   = (const float*)d_in[0];
    const float* adj  = (const float*)d_in[1];
    const float* mask = (const float*)d_in[2];
    const float* g_w[3]  = {(const float*)d_in[4],  (const float*)d_in[8],  (const float*)d_in[12]};
    const float* g_b[3]  = {(const float*)d_in[5],  (const float*)d_in[9],  (const float*)d_in[13]};
    const float* g_aw[3] = {(const float*)d_in[6],  (const float*)d_in[10], (const float*)d_in[14]};
    const float* g_ab[3] = {(const float*)d_in[7],  (const float*)d_in[11], (const float*)d_in[15]};
    const float* wih0f = (const float*)d_in[16]; const float* whh0f = (const float*)d_in[17]; const float* b0f = (const float*)d_in[18];
    const float* wih0b = (const float*)d_in[19]; const float* whh0b = (const float*)d_in[20]; const float* b0b = (const float*)d_in[21];
    const float* wih1f = (const float*)d_in[22]; const float* whh1f = (const float*)d_in[23]; const float* b1f = (const float*)d_in[24];
    const float* wih1b = (const float*)d_in[25]; const float* whh1b = (const float*)d_in[26]; const float* b1b = (const float*)d_in[27];

    float* ws = (float*)d_ws;
    // Workspace layout (floats); total ~15.7M floats = ~63 MB (unchanged).
    float* bufA = ws;                       // (4096,256)
    float* bufB = bufA + 1048576;           // (4096,256); later f16 scan weights + sync
    float* bufC = bufB + 1048576;           // (4096,256) GNN3 output
    float* si   = bufC + 1048576;           // (4096)
    float* sj   = si + 4096;                // (4096)
    float* out0 = sj + 4096;                // (4096,512)
    float* out1 = out0 + 2097152;           // (4096,512)
    float* P0   = out1 + 2097152;           // (4096,1024)
    float* P1   = P0 + 4194304;             // (4096,1024)
    float* watt = P0;                       // alias (GNN phase only)
    // f16 scan weights in bufB first half (dead after GNN3):
    unsigned int* w16_0f = (unsigned int*)bufB;
    unsigned int* w16_0b = w16_0f + 131072;
    unsigned int* w16_1f = w16_0b + 131072;
    unsigned int* w16_1b = w16_1f + 131072;
    // scan sync state in bufB second half: hb u32[2][16][2][64]=4096, fl int[32]
    unsigned int* hb = (unsigned int*)bufB + 524288;
    int*          fl = (int*)(hb + 4096);
    const int SYNC_U32 = 4096 + 32;
    // bf16 scratch, aliased into phase-dead regions:
    unsigned short* nfp   = (unsigned short*)P1;                 // 524288 e
    unsigned short* bufBp = (unsigned short*)(P1 + 262144);      // 1048576 e
    unsigned short* gwp1  = (unsigned short*)(P1 + 786432);      // 32768 e
    unsigned short* gwp2  = (unsigned short*)(P1 + 802816);      // 65536 e
    unsigned short* gwp3  = (unsigned short*)(P1 + 835584);      // 65536 e
    unsigned short* bufCp  = (unsigned short*)bufA;              // 1048576 e
    unsigned short* out0p  = (unsigned short*)bufA;              // 2097152 e
    unsigned short* wih0fp = (unsigned short*)out1;              // 262144 e
    unsigned short* wih0bp = (unsigned short*)(out1 + 131072);   // 262144 e
    unsigned short* wih1fp = (unsigned short*)(out1 + 262144);   // 524288 e
    unsigned short* wih1bp = (unsigned short*)(out1 + 524288);   // 524288 e
    unsigned short* out1p  = (unsigned short*)P0;                // 2097152 e
    unsigned short* bufCp2 = (unsigned short*)(P0 + 1048576);    // 1048576 e
    unsigned short* opw1p  = (unsigned short*)(P0 + 1572864);    // 131072 e
    unsigned short* ppw1p  = (unsigned short*)(P0 + 1638400);    // 131072 e
    unsigned short* skw1p  = (unsigned short*)(P0 + 1703936);    // 131072 e
    unsigned short* ndw1p  = (unsigned short*)(P0 + 1769472);    // 65536 e

    const int MR = BB * NN;                 // 4096 rows
    dim3 blk(256);

    // ---------------- GNN x3 (projections via MFMA) ----------------
    pack3_bf16<<<dim3(608), blk, 0, stream>>>(nf, nfp, 524288,
                                              g_w[0], gwp1, 32768,
                                              g_w[1], gwp2, 65536);
    auto run_attn = [&](int li, float* ob, bool relu) {
        attn_sisj<<<dim3(MR / 4), blk, 0, stream>>>(bufA, g_aw[li], g_ab[li], si, sj);
        attn_score<<<dim3(MR), dim3(512), 0, stream>>>(si, sj, adj, mask, watt);
        if (relu)
            gemm_nn_mask<1><<<dim3(HDIM / 64, NN / 64, BB), blk, 0, stream>>>(watt, bufA, mask, ob, NN, NN, HDIM);
        else
            gemm_nn_mask<0><<<dim3(HDIM / 64, NN / 64, BB), blk, 0, stream>>>(watt, bufA, mask, ob, NN, NN, HDIM);
    };
    gemm_nt_mfma<0><<<dim3(2, 32), blk, 0, stream>>>(nfp, gwp1, g_b[0], bufA, NDIM, HDIM);
    run_attn(0, bufB, true);
    pack3_bf16<<<dim3(1088), blk, 0, stream>>>(bufB, bufBp, 1048576,
                                               g_w[2], gwp3, 65536,
                                               (const float*)0, (unsigned short*)0, 0);
    gemm_nt_mfma<0><<<dim3(2, 32), blk, 0, stream>>>(bufBp, gwp2, g_b[1], bufA, HDIM, HDIM);
    run_attn(1, bufB, true);
    pack3_bf16<<<dim3(1024), blk, 0, stream>>>(bufB, bufBp, 1048576,
                                               (const float*)0, (unsigned short*)0, 0,
                                               (const float*)0, (unsigned short*)0, 0);
    gemm_nt_mfma<0><<<dim3(2, 32), blk, 0, stream>>>(bufBp, gwp3, g_b[2], bufA, HDIM, HDIM);
    run_attn(2, bufC, false);

    // ---------------- pack scan whh weights to f16 (bufB now dead) ----------
    pack_f16<<<dim3(512), blk, 0, stream>>>(whh0f, w16_0f, 131072);
    pack_f16<<<dim3(512), blk, 0, stream>>>(whh0b, w16_0b, 131072);
    pack_f16<<<dim3(512), blk, 0, stream>>>(whh1f, w16_1f, 131072);
    pack_f16<<<dim3(512), blk, 0, stream>>>(whh1b, w16_1b, 131072);

    // ---------------- LSTM layer 0 ----------------
    pack3_bf16<<<dim3(1536), blk, 0, stream>>>(bufC, bufCp, 1048576,
                                               wih0f, wih0fp, 262144,
                                               wih0b, wih0bp, 262144);
    gemm_nt_mfma<0><<<dim3(8, 32), blk, 0, stream>>>(bufCp, wih0fp, b0f, P0, HDIM, 1024);
    gemm_nt_mfma<0><<<dim3(8, 32), blk, 0, stream>>>(bufCp, wih0bp, b0b, P1, HDIM, 1024);
    zero_ws<<<dim3(8), blk, 0, stream>>>(hb, SYNC_U32);
    lstm_scan8<<<dim3(32), dim3(512), 0, stream>>>(P0, P1, w16_0f, w16_0b, out0, hb, fl);

    // ---------------- LSTM layer 1 ----------------
    pack3_bf16<<<dim3(3072), blk, 0, stream>>>(out0, out0p, 2097152,
                                               wih1f, wih1fp, 524288,
                                               wih1b, wih1bp, 524288);
    gemm_nt_mfma<0><<<dim3(8, 32), blk, 0, stream>>>(out0p, wih1fp, b1f, P0, 512, 1024);
    gemm_nt_mfma<0><<<dim3(8, 32), blk, 0, stream>>>(out0p, wih1bp, b1b, P1, 512, 1024);
    zero_ws<<<dim3(8), blk, 0, stream>>>(hb, SYNC_U32);
    lstm_scan8<<<dim3(32), dim3(512), 0, stream>>>(P0, P1, w16_1f, w16_1b, out1, hb, fl);

    // ---------------- Heads ----------------
    float* out = (float*)d_out;
    pack3_bf16<<<dim3(3200), blk, 0, stream>>>(out1, out1p, 2097152,
                                               bufC, bufCp2, 1048576,
                                               (const float*)d_in[28], opw1p, 131072);
    pack3_bf16<<<dim3(320), blk, 0, stream>>>((const float*)d_in[32], ppw1p, 131072,
                                              (const float*)d_in[36], skw1p, 131072,
                                              (const float*)d_in[40], ndw1p, 65536);
    // op: (B,N,64) at offset 0
    gemm_nt_mfma<1><<<dim3(2, 32), blk, 0, stream>>>(out1p, opw1p, (const float*)d_in[29], bufA, 512, 256);
    gemm_nt<0><<<dim3(1, MR / 64), blk, 0, stream>>>(bufA, (const float*)d_in[30], (const float*)d_in[31], out, MR, 256, 64);
    // pp: (B,N,16) at offset 262144
    gemm_nt_mfma<1><<<dim3(2, 32), blk, 0, stream>>>(out1p, ppw1p, (const float*)d_in[33], bufA, 512, 256);
    gemm_nt<0><<<dim3(1, MR / 64), blk, 0, stream>>>(bufA, (const float*)d_in[34], (const float*)d_in[35], out + 262144, MR, 256, 16);
    // sk: (B,N,128) at offset 327680
    gemm_nt_mfma<1><<<dim3(2, 32), blk, 0, stream>>>(out1p, skw1p, (const float*)d_in[37], bufA, 512, 256);
    gemm_nt<0><<<dim3(2, MR / 64), blk, 0, stream>>>(bufA, (const float*)d_in[38], (const float*)d_in[39], out + 327680, MR, 256, 128);
    // nd: (B,N,128) at offset 851968 (input = GNN3 output)
    gemm_nt_mfma<1><<<dim3(2, 32), blk, 0, stream>>>(bufCp2, ndw1p, (const float*)d_in[41], bufA, 256, 256);
    gemm_nt<0><<<dim3(2, MR / 64), blk, 0, stream>>>(bufA, (const float*)d_in[42], (const float*)d_in[43], out + 851968, MR, 256, 128);
}

// Round 13
// 3199.143 us; speedup vs baseline: 1.2795x; 1.2795x over previous
//
#include <hip/hip_runtime.h>

// Problem constants (DeepCAD_1958505087412)
#define BB   8
#define NN   512      // nodes == timesteps
#define NDIM 128
#define HDIM 256      // GNN out dim == LSTM hidden
#define TT   512

__device__ __forceinline__ float sigmoidf_(float x) { return 1.0f / (1.0f + __expf(-x)); }
__device__ __forceinline__ float tanhf_(float x) { float e = __expf(2.0f * x); return 1.0f - 2.0f / (e + 1.0f); }

typedef _Float16 half2v __attribute__((ext_vector_type(2)));
typedef unsigned int uint4v __attribute__((ext_vector_type(4)));
typedef short bf16x8 __attribute__((ext_vector_type(8)));
typedef float f32x4 __attribute__((ext_vector_type(4)));
__device__ __forceinline__ float fdot2_(unsigned int w, unsigned int h, float acc) {
    return __builtin_amdgcn_fdot2(__builtin_bit_cast(half2v, w),
                                  __builtin_bit_cast(half2v, h), acc, false);
}
__device__ __forceinline__ unsigned short f2bf_(float x) {
    unsigned int u = __builtin_bit_cast(unsigned int, x);
    return (unsigned short)((u + 0x7FFFu + ((u >> 16) & 1u)) >> 16);   // RNE
}
__device__ __forceinline__ unsigned short f2h_(float x) {
    _Float16 h = (_Float16)x;
    return *(unsigned short*)&h;
}

// ---------------------------------------------------------------------------
// fp32 Y = X @ W^T + bias (optional ReLU) — small head layer-2 GEMMs.
// ---------------------------------------------------------------------------
template<int RELU>
__global__ __launch_bounds__(256) void gemm_nt(const float* __restrict__ X,
    const float* __restrict__ W, const float* __restrict__ bias,
    float* __restrict__ Y, int M, int K, int Nn)
{
    __shared__ float Xs[16][68];
    __shared__ float Ws[16][68];
    const int tid = threadIdx.x;
    const int m0 = blockIdx.y << 6;
    const int n0 = blockIdx.x << 6;
    const int lr = tid >> 2;
    const int lc = (tid & 3) << 2;
    const int tm = (tid >> 4) << 2;
    const int tn = (tid & 15) << 2;

    float acc[4][4] = {{0.f,0.f,0.f,0.f},{0.f,0.f,0.f,0.f},{0.f,0.f,0.f,0.f},{0.f,0.f,0.f,0.f}};

    const float* Xp = X + (size_t)(m0 + lr) * K + lc;
    const bool wok = (n0 + lr) < Nn;
    const float* Wp = wok ? (W + (size_t)(n0 + lr) * K + lc) : W;

    for (int k0 = 0; k0 < K; k0 += 16) {
        float4 xv = *(const float4*)(Xp + k0);
        float4 wv = *(const float4*)(Wp + k0);
        if (!wok) wv = make_float4(0.f, 0.f, 0.f, 0.f);
        __syncthreads();
        Xs[lc+0][lr]=xv.x; Xs[lc+1][lr]=xv.y; Xs[lc+2][lr]=xv.z; Xs[lc+3][lr]=xv.w;
        Ws[lc+0][lr]=wv.x; Ws[lc+1][lr]=wv.y; Ws[lc+2][lr]=wv.z; Ws[lc+3][lr]=wv.w;
        __syncthreads();
        #pragma unroll
        for (int kk = 0; kk < 16; ++kk) {
            const float4 a = *(const float4*)(&Xs[kk][tm]);
            const float4 b = *(const float4*)(&Ws[kk][tn]);
            acc[0][0] += a.x*b.x; acc[0][1] += a.x*b.y; acc[0][2] += a.x*b.z; acc[0][3] += a.x*b.w;
            acc[1][0] += a.y*b.x; acc[1][1] += a.y*b.y; acc[1][2] += a.y*b.z; acc[1][3] += a.y*b.w;
            acc[2][0] += a.z*b.x; acc[2][1] += a.z*b.y; acc[2][2] += a.z*b.z; acc[2][3] += a.z*b.w;
            acc[3][0] += a.w*b.x; acc[3][1] += a.w*b.y; acc[3][2] += a.w*b.z; acc[3][3] += a.w*b.w;
        }
    }
    const int nc = n0 + tn;
    if (nc >= Nn) return;
    float4 bv = make_float4(0.f, 0.f, 0.f, 0.f);
    if (bias) bv = *(const float4*)(bias + nc);
    #pragma unroll
    for (int i = 0; i < 4; ++i) {
        float4 o;
        o.x = acc[i][0] + bv.x; o.y = acc[i][1] + bv.y;
        o.z = acc[i][2] + bv.z; o.w = acc[i][3] + bv.w;
        if (RELU) { o.x=fmaxf(o.x,0.f); o.y=fmaxf(o.y,0.f); o.z=fmaxf(o.z,0.f); o.w=fmaxf(o.w,0.f); }
        *(float4*)(Y + (size_t)(m0 + tm + i) * Nn + nc) = o;
    }
}

// ---------------------------------------------------------------------------
// bf16 MFMA Y = X @ W^T + bias (optional ReLU). Verified r10/r11.
// ---------------------------------------------------------------------------
template<int RELU>
__global__ __launch_bounds__(256) void gemm_nt_mfma(
    const unsigned short* __restrict__ X, const unsigned short* __restrict__ W,
    const float* __restrict__ bias, float* __restrict__ Y, int K, int Nn)
{
    __shared__ unsigned short As[128][56];
    __shared__ unsigned short Bs[128][56];
    const int tid = threadIdx.x;
    const int m0 = blockIdx.y << 7;
    const int n0 = blockIdx.x << 7;
    const int wid = tid >> 6, lane = tid & 63;
    const int wm = (wid >> 1) << 6;
    const int wn = (wid & 1) << 6;
    const int sr = tid >> 2;
    const int sc = (tid & 3) << 3;

    f32x4 acc[4][4] = {};

    const int fr = lane & 15;
    const int kg = (lane >> 4) << 3;

    for (int k0 = 0; k0 < K; k0 += 32) {
        uint4 a0 = *(const uint4*)(X + (size_t)(m0 + sr) * K + k0 + sc);
        uint4 a1 = *(const uint4*)(X + (size_t)(m0 + sr + 64) * K + k0 + sc);
        uint4 b0 = *(const uint4*)(W + (size_t)(n0 + sr) * K + k0 + sc);
        uint4 b1 = *(const uint4*)(W + (size_t)(n0 + sr + 64) * K + k0 + sc);
        __syncthreads();
        *(uint4*)&As[sr][sc] = a0; *(uint4*)&As[sr + 64][sc] = a1;
        *(uint4*)&Bs[sr][sc] = b0; *(uint4*)&Bs[sr + 64][sc] = b1;
        __syncthreads();
        bf16x8 af[4], bf[4];
        #pragma unroll
        for (int i = 0; i < 4; ++i) {
            af[i] = *(const bf16x8*)&As[wm + i * 16 + fr][kg];
            bf[i] = *(const bf16x8*)&Bs[wn + i * 16 + fr][kg];
        }
        #pragma unroll
        for (int i = 0; i < 4; ++i)
            #pragma unroll
            for (int j = 0; j < 4; ++j)
                acc[i][j] = __builtin_amdgcn_mfma_f32_16x16x32_bf16(af[i], bf[j], acc[i][j], 0, 0, 0);
    }

    const int cr = (lane >> 4) << 2;
    const int cc = lane & 15;
    #pragma unroll
    for (int i = 0; i < 4; ++i) {
        #pragma unroll
        for (int j = 0; j < 4; ++j) {
            const int col = n0 + wn + j * 16 + cc;
            const float bv = bias ? bias[col] : 0.f;
            #pragma unroll
            for (int r = 0; r < 4; ++r) {
                const int row = m0 + wm + i * 16 + cr + r;
                float v = acc[i][j][r] + bv;
                if (RELU) v = fmaxf(v, 0.f);
                Y[(size_t)row * Nn + col] = v;
            }
        }
    }
}

// ---------------------------------------------------------------------------
// Batched Y[b] = (A[b] @ H[b]) * mask[b,:,None], optional ReLU (fp32).
// ---------------------------------------------------------------------------
template<int RELU>
__global__ __launch_bounds__(256) void gemm_nn_mask(const float* __restrict__ A,
    const float* __restrict__ Hm, const float* __restrict__ mask,
    float* __restrict__ Y, int M, int K, int Nn)
{
    const int b = blockIdx.z;
    A  += (size_t)b * M * K;
    Hm += (size_t)b * K * Nn;
    Y  += (size_t)b * M * Nn;
    __shared__ float As[16][68];
    __shared__ float Hs[16][68];
    const int tid = threadIdx.x;
    const int m0 = blockIdx.y << 6;
    const int n0 = blockIdx.x << 6;
    const int lr = tid >> 2;
    const int lc = (tid & 3) << 2;
    const int hr = tid >> 4;
    const int hc = (tid & 15) << 2;
    const int tm = (tid >> 4) << 2;
    const int tn = (tid & 15) << 2;

    float acc[4][4] = {{0.f,0.f,0.f,0.f},{0.f,0.f,0.f,0.f},{0.f,0.f,0.f,0.f},{0.f,0.f,0.f,0.f}};

    for (int k0 = 0; k0 < K; k0 += 16) {
        float4 av = *(const float4*)(A + (size_t)(m0 + lr) * K + k0 + lc);
        float4 hv = *(const float4*)(Hm + (size_t)(k0 + hr) * Nn + n0 + hc);
        __syncthreads();
        As[lc+0][lr]=av.x; As[lc+1][lr]=av.y; As[lc+2][lr]=av.z; As[lc+3][lr]=av.w;
        *(float4*)(&Hs[hr][hc]) = hv;
        __syncthreads();
        #pragma unroll
        for (int kk = 0; kk < 16; ++kk) {
            const float4 a = *(const float4*)(&As[kk][tm]);
            const float4 h = *(const float4*)(&Hs[kk][tn]);
            acc[0][0] += a.x*h.x; acc[0][1] += a.x*h.y; acc[0][2] += a.x*h.z; acc[0][3] += a.x*h.w;
            acc[1][0] += a.y*h.x; acc[1][1] += a.y*h.y; acc[1][2] += a.y*h.z; acc[1][3] += a.y*h.w;
            acc[2][0] += a.z*h.x; acc[2][1] += a.z*h.y; acc[2][2] += a.z*h.z; acc[2][3] += a.z*h.w;
            acc[3][0] += a.w*h.x; acc[3][1] += a.w*h.y; acc[3][2] += a.w*h.z; acc[3][3] += a.w*h.w;
        }
    }
    #pragma unroll
    for (int i = 0; i < 4; ++i) {
        const float mk = mask[b * M + m0 + tm + i];
        float4 o;
        o.x = acc[i][0]*mk; o.y = acc[i][1]*mk; o.z = acc[i][2]*mk; o.w = acc[i][3]*mk;
        if (RELU) { o.x=fmaxf(o.x,0.f); o.y=fmaxf(o.y,0.f); o.z=fmaxf(o.z,0.f); o.w=fmaxf(o.w,0.f); }
        *(float4*)(Y + (size_t)(m0 + tm + i) * Nn + n0 + tn) = o;
    }
}

// ---------------------------------------------------------------------------
__global__ __launch_bounds__(256) void attn_sisj(const float* __restrict__ h,
    const float* __restrict__ aw, const float* __restrict__ ab,
    float* __restrict__ si, float* __restrict__ sj)
{
    const int lane = threadIdx.x & 63;
    const int row  = (blockIdx.x << 2) + (threadIdx.x >> 6);
    const float4 hv = ((const float4*)(h + (size_t)row * HDIM))[lane];
    const float4 a1 = ((const float4*)aw)[lane];
    const float4 a2 = ((const float4*)(aw + HDIM))[lane];
    float s1 = hv.x*a1.x + hv.y*a1.y + hv.z*a1.z + hv.w*a1.w;
    float s2 = hv.x*a2.x + hv.y*a2.y + hv.z*a2.z + hv.w*a2.w;
    #pragma unroll
    for (int off = 32; off > 0; off >>= 1) {
        s1 += __shfl_down(s1, off);
        s2 += __shfl_down(s2, off);
    }
    if (lane == 0) { si[row] = s1 + ab[0]; sj[row] = s2; }
}

// ---------------------------------------------------------------------------
__global__ __launch_bounds__(512) void attn_score(const float* __restrict__ si,
    const float* __restrict__ sj, const float* __restrict__ adj,
    const float* __restrict__ mask, float* __restrict__ watt)
{
    const int bi = blockIdx.x;
    const int b  = bi >> 9;
    const int j  = threadIdx.x;
    const float s0 = si[bi];
    const float mi = mask[bi];
    float s = sigmoidf_(s0 + sj[(b << 9) + j]) * adj[(size_t)bi * NN + j] * mi * mask[(b << 9) + j];
    float t = s;
    #pragma unroll
    for (int off = 32; off > 0; off >>= 1) t += __shfl_down(t, off);
    __shared__ float red[8];
    const int lane = j & 63, wv = j >> 6;
    if (lane == 0) red[wv] = t;
    __syncthreads();
    if (j == 0) {
        float tot = 0.f;
        #pragma unroll
        for (int w = 0; w < 8; ++w) tot += red[w];
        red[0] = 1.0f / (tot + 1e-8f);
    }
    __syncthreads();
    watt[(size_t)bi * NN + j] = s * red[0];
}

// ---------------------------------------------------------------------------
__global__ __launch_bounds__(256) void pack_f16(const float* __restrict__ src,
    unsigned int* __restrict__ dst, int n)
{
    int i = blockIdx.x * 256 + threadIdx.x;
    if (i < n) {
        float2 v = ((const float2*)src)[i];
        dst[i] = (unsigned int)f2h_(v.x) | ((unsigned int)f2h_(v.y) << 16);
    }
}

// ---------------------------------------------------------------------------
__global__ __launch_bounds__(256) void pack3_bf16(
    const float* __restrict__ s0, unsigned short* __restrict__ d0, int n0,
    const float* __restrict__ s1, unsigned short* __restrict__ d1, int n1,
    const float* __restrict__ s2, unsigned short* __restrict__ d2, int n2)
{
    int i = (blockIdx.x * 256 + threadIdx.x) * 4;
    const float* s; unsigned short* d; int l;
    if (i < n0) { s = s0; d = d0; l = i; }
    else if (i < n0 + n1) { s = s1; d = d1; l = i - n0; }
    else if (i < n0 + n1 + n2) { s = s2; d = d2; l = i - n0 - n1; }
    else return;
    float4 v = *(const float4*)(s + l);
    ushort4 o;
    o.x = f2bf_(v.x); o.y = f2bf_(v.y); o.z = f2bf_(v.z); o.w = f2bf_(v.w);
    *(ushort4*)(d + l) = o;
}

// ---------------------------------------------------------------------------
// Single-block-per-chain LSTM scan, weights in AGPRs (write-once, read-only).
// r5-r9: the RA caps arch VGPRs at 64-128 and never holds the 96 weight
// dwords -> 384 KB/step L2 re-stream = 1.92 us/step floor. r8's AGPR attempt
// failed from BIDIRECTIONAL copy storms (per-iteration "+a" re-pin). Fix:
// pin the 96 dwords into AGPR class ONCE before the loop (volatile asm
// result -> not rematerializable, r5 bug blocked); in-loop, explicit
// one-directional v_accvgpr_read copies (96 x 2cyc x 4 waves/SIMD ~ 0.32
// us/step) feed the fdot2s. Demand: ~96 AGPR + ~45 arch VGPR -> fits under
// every RA budget tier; AGPR spill is costly so RA should hold them.
// Geometry as scan7: 16 blocks (chain), 1024 thr (1 gate row each),
// k 192..255 in LDS (128 KB, lane-contiguous), h packed f16 in LDS.
// ---------------------------------------------------------------------------
__global__ __launch_bounds__(1024) __attribute__((amdgpu_waves_per_eu(4, 4)))
void lstm_scan9(
    const float* __restrict__ pre_f, const float* __restrict__ pre_b,
    const unsigned int* __restrict__ w16_f, const unsigned int* __restrict__ w16_b,
    float* __restrict__ out)
{
    __shared__ uint4v lw4[8 * 1024];        // 128 KB: quads 24..31 of each row
    __shared__ float g_s[1024];
    __shared__ unsigned int h2[128];

    const int chain = blockIdx.x;
    const int batch = chain >> 1;
    const int dir   = chain & 1;
    const float* pre = dir ? pre_b : pre_f;
    const unsigned int* w = dir ? w16_b : w16_f;
    const int t0 = threadIdx.x;             // gate row 0..1023

    const uint4v* wr = (const uint4v*)(w + (size_t)t0 * 128);

    // LDS tail (quads 24..31, lane-contiguous = conflict-free)
    #pragma unroll
    for (int i = 0; i < 8; ++i) lw4[i * 1024 + t0] = wr[24 + i];

    // quads 0..23 -> 96 scalar dwords, pinned ONCE into AGPR class.
#define LOADQ(q) const uint4v T##q = wr[q]; \
    unsigned int W##q##_0 = T##q.x, W##q##_1 = T##q.y, W##q##_2 = T##q.z, W##q##_3 = T##q.w; \
    asm volatile("" : "+a"(W##q##_0), "+a"(W##q##_1), "+a"(W##q##_2), "+a"(W##q##_3));
    LOADQ(0) LOADQ(1) LOADQ(2) LOADQ(3) LOADQ(4) LOADQ(5) LOADQ(6) LOADQ(7)
    LOADQ(8) LOADQ(9) LOADQ(10) LOADQ(11) LOADQ(12) LOADQ(13) LOADQ(14) LOADQ(15)
    LOADQ(16) LOADQ(17) LOADQ(18) LOADQ(19) LOADQ(20) LOADQ(21) LOADQ(22) LOADQ(23)
#undef LOADQ

    if (t0 < 128) h2[t0] = 0u;
    float c = 0.f;

    const int tt0 = dir ? (TT - 1) : 0;
    const long pstep = dir ? -1024 : 1024;
    const long ostep = dir ? -512 : 512;
    const float* pp = pre + ((size_t)batch * TT + tt0) * 1024 + t0;
    float* op = out + ((size_t)batch * TT + tt0) * 512 + dir * 256 + t0;  // t0<256
    float pv = *pp; pp += pstep;
    __syncthreads();

    for (int t = 0; t < TT; ++t) {
        float pv_n = 0.f;
        if (t + 1 < TT) pv_n = *pp;
        pp += pstep;

        float a0 = 0.f, a1 = 0.f, a2 = 0.f, a3 = 0.f;
        const uint4v* h4 = (const uint4v*)h2;
        // quads 0..23: explicit AGPR->VGPR reads (one-directional) + dots
#define DOTQ(q) { \
        unsigned int w0, w1, w2, w3; \
        asm volatile("v_accvgpr_read_b32 %0, %4\n\t" \
                     "v_accvgpr_read_b32 %1, %5\n\t" \
                     "v_accvgpr_read_b32 %2, %6\n\t" \
                     "v_accvgpr_read_b32 %3, %7" \
            : "=v"(w0), "=v"(w1), "=v"(w2), "=v"(w3) \
            : "a"(W##q##_0), "a"(W##q##_1), "a"(W##q##_2), "a"(W##q##_3)); \
        const uint4v hv = h4[q]; \
        a0 = fdot2_(w0, hv.x, a0); a1 = fdot2_(w1, hv.y, a1); \
        a2 = fdot2_(w2, hv.z, a2); a3 = fdot2_(w3, hv.w, a3); }
        DOTQ(0) DOTQ(1) DOTQ(2) DOTQ(3) DOTQ(4) DOTQ(5) DOTQ(6) DOTQ(7)
        DOTQ(8) DOTQ(9) DOTQ(10) DOTQ(11) DOTQ(12) DOTQ(13) DOTQ(14) DOTQ(15)
        DOTQ(16) DOTQ(17) DOTQ(18) DOTQ(19) DOTQ(20) DOTQ(21) DOTQ(22) DOTQ(23)
#undef DOTQ
        // quads 24..31 from LDS
        #pragma unroll
        for (int i = 0; i < 8; ++i) {
            const uint4v wv = lw4[i * 1024 + t0];
            const uint4v hv = h4[24 + i];
            a0 = fdot2_(wv.x, hv.x, a0); a1 = fdot2_(wv.y, hv.y, a1);
            a2 = fdot2_(wv.z, hv.z, a2); a3 = fdot2_(wv.w, hv.w, a3);
        }
        g_s[t0] = (a0 + a1) + (a2 + a3) + pv;
        __syncthreads();
        if (t0 < 256) {
            const float ig = sigmoidf_(g_s[t0]);
            const float fg = sigmoidf_(g_s[256 + t0]);
            const float gg = tanhf_(g_s[512 + t0]);
            const float og = sigmoidf_(g_s[768 + t0]);
            c = fg * c + ig * gg;
            const float h = og * tanhf_(c);
            *op = h;
            op += ostep;
            ((unsigned short*)h2)[t0] = f2h_(h);
        }
        pv = pv_n;
        __syncthreads();
    }
}

// ---------------------------------------------------------------------------

extern "C" void kernel_launch(void* const* d_in, const int* in_sizes, int n_in,
                              void* d_out, int out_size, void* d_ws, size_t ws_size,
                              hipStream_t stream)
{
    const float* nf   = (const float*)d_in[0];
    const float* adj  = (const float*)d_in[1];
    const float* mask = (const float*)d_in[2];
    const float* g_w[3]  = {(const float*)d_in[4],  (const float*)d_in[8],  (const float*)d_in[12]};
    const float* g_b[3]  = {(const float*)d_in[5],  (const float*)d_in[9],  (const float*)d_in[13]};
    const float* g_aw[3] = {(const float*)d_in[6],  (const float*)d_in[10], (const float*)d_in[14]};
    const float* g_ab[3] = {(const float*)d_in[7],  (const float*)d_in[11], (const float*)d_in[15]};
    const float* wih0f = (const float*)d_in[16]; const float* whh0f = (const float*)d_in[17]; const float* b0f = (const float*)d_in[18];
    const float* wih0b = (const float*)d_in[19]; const float* whh0b = (const float*)d_in[20]; const float* b0b = (const float*)d_in[21];
    const float* wih1f = (const float*)d_in[22]; const float* whh1f = (const float*)d_in[23]; const float* b1f = (const float*)d_in[24];
    const float* wih1b = (const float*)d_in[25]; const float* whh1b = (const float*)d_in[26]; const float* b1b = (const float*)d_in[27];

    float* ws = (float*)d_ws;
    // Workspace layout (floats); total ~15.7M floats = ~63 MB (unchanged).
    float* bufA = ws;                       // (4096,256)
    float* bufB = bufA + 1048576;           // (4096,256); later f16 scan weights
    float* bufC = bufB + 1048576;           // (4096,256) GNN3 output
    float* si   = bufC + 1048576;           // (4096)
    float* sj   = si + 4096;                // (4096)
    float* out0 = sj + 4096;                // (4096,512)
    float* out1 = out0 + 2097152;           // (4096,512)
    float* P0   = out1 + 2097152;           // (4096,1024)
    float* P1   = P0 + 4194304;             // (4096,1024)
    float* watt = P0;                       // alias (GNN phase only)
    // f16 scan weights in bufB (dead after GNN3):
    unsigned int* w16_0f = (unsigned int*)bufB;
    unsigned int* w16_0b = w16_0f + 131072;
    unsigned int* w16_1f = w16_0b + 131072;
    unsigned int* w16_1b = w16_1f + 131072;
    // bf16 scratch, aliased into phase-dead regions:
    unsigned short* nfp   = (unsigned short*)P1;                 // 524288 e
    unsigned short* bufBp = (unsigned short*)(P1 + 262144);      // 1048576 e
    unsigned short* gwp1  = (unsigned short*)(P1 + 786432);      // 32768 e
    unsigned short* gwp2  = (unsigned short*)(P1 + 802816);      // 65536 e
    unsigned short* gwp3  = (unsigned short*)(P1 + 835584);      // 65536 e
    unsigned short* bufCp  = (unsigned short*)bufA;              // 1048576 e
    unsigned short* out0p  = (unsigned short*)bufA;              // 2097152 e
    unsigned short* wih0fp = (unsigned short*)out1;              // 262144 e
    unsigned short* wih0bp = (unsigned short*)(out1 + 131072);   // 262144 e
    unsigned short* wih1fp = (unsigned short*)(out1 + 262144);   // 524288 e
    unsigned short* wih1bp = (unsigned short*)(out1 + 524288);   // 524288 e
    unsigned short* out1p  = (unsigned short*)P0;                // 2097152 e
    unsigned short* bufCp2 = (unsigned short*)(P0 + 1048576);    // 1048576 e
    unsigned short* opw1p  = (unsigned short*)(P0 + 1572864);    // 131072 e
    unsigned short* ppw1p  = (unsigned short*)(P0 + 1638400);    // 131072 e
    unsigned short* skw1p  = (unsigned short*)(P0 + 1703936);    // 131072 e
    unsigned short* ndw1p  = (unsigned short*)(P0 + 1769472);    // 65536 e

    const int MR = BB * NN;                 // 4096 rows
    dim3 blk(256);

    // ---------------- GNN x3 (projections via MFMA) ----------------
    pack3_bf16<<<dim3(608), blk, 0, stream>>>(nf, nfp, 524288,
                                              g_w[0], gwp1, 32768,
                                              g_w[1], gwp2, 65536);
    auto run_attn = [&](int li, float* ob, bool relu) {
        attn_sisj<<<dim3(MR / 4), blk, 0, stream>>>(bufA, g_aw[li], g_ab[li], si, sj);
        attn_score<<<dim3(MR), dim3(512), 0, stream>>>(si, sj, adj, mask, watt);
        if (relu)
            gemm_nn_mask<1><<<dim3(HDIM / 64, NN / 64, BB), blk, 0, stream>>>(watt, bufA, mask, ob, NN, NN, HDIM);
        else
            gemm_nn_mask<0><<<dim3(HDIM / 64, NN / 64, BB), blk, 0, stream>>>(watt, bufA, mask, ob, NN, NN, HDIM);
    };
    gemm_nt_mfma<0><<<dim3(2, 32), blk, 0, stream>>>(nfp, gwp1, g_b[0], bufA, NDIM, HDIM);
    run_attn(0, bufB, true);
    pack3_bf16<<<dim3(1088), blk, 0, stream>>>(bufB, bufBp, 1048576,
                                               g_w[2], gwp3, 65536,
                                               (const float*)0, (unsigned short*)0, 0);
    gemm_nt_mfma<0><<<dim3(2, 32), blk, 0, stream>>>(bufBp, gwp2, g_b[1], bufA, HDIM, HDIM);
    run_attn(1, bufB, true);
    pack3_bf16<<<dim3(1024), blk, 0, stream>>>(bufB, bufBp, 1048576,
                                               (const float*)0, (unsigned short*)0, 0,
                                               (const float*)0, (unsigned short*)0, 0);
    gemm_nt_mfma<0><<<dim3(2, 32), blk, 0, stream>>>(bufBp, gwp3, g_b[2], bufA, HDIM, HDIM);
    run_attn(2, bufC, false);

    // ---------------- pack scan whh weights to f16 (bufB now dead) ----------
    pack_f16<<<dim3(512), blk, 0, stream>>>(whh0f, w16_0f, 131072);
    pack_f16<<<dim3(512), blk, 0, stream>>>(whh0b, w16_0b, 131072);
    pack_f16<<<dim3(512), blk, 0, stream>>>(whh1f, w16_1f, 131072);
    pack_f16<<<dim3(512), blk, 0, stream>>>(whh1b, w16_1b, 131072);

    // ---------------- LSTM layer 0 ----------------
    pack3_bf16<<<dim3(1536), blk, 0, stream>>>(bufC, bufCp, 1048576,
                                               wih0f, wih0fp, 262144,
                                               wih0b, wih0bp, 262144);
    gemm_nt_mfma<0><<<dim3(8, 32), blk, 0, stream>>>(bufCp, wih0fp, b0f, P0, HDIM, 1024);
    gemm_nt_mfma<0><<<dim3(8, 32), blk, 0, stream>>>(bufCp, wih0bp, b0b, P1, HDIM, 1024);
    lstm_scan9<<<dim3(16), dim3(1024), 0, stream>>>(P0, P1, w16_0f, w16_0b, out0);

    // ---------------- LSTM layer 1 ----------------
    pack3_bf16<<<dim3(3072), blk, 0, stream>>>(out0, out0p, 2097152,
                                               wih1f, wih1fp, 524288,
                                               wih1b, wih1bp, 524288);
    gemm_nt_mfma<0><<<dim3(8, 32), blk, 0, stream>>>(out0p, wih1fp, b1f, P0, 512, 1024);
    gemm_nt_mfma<0><<<dim3(8, 32), blk, 0, stream>>>(out0p, wih1bp, b1b, P1, 512, 1024);
    lstm_scan9<<<dim3(16), dim3(1024), 0, stream>>>(P0, P1, w16_1f, w16_1b, out1);

    // ---------------- Heads ----------------
    float* out = (float*)d_out;
    pack3_bf16<<<dim3(3200), blk, 0, stream>>>(out1, out1p, 2097152,
                                               bufC, bufCp2, 1048576,
                                               (const float*)d_in[28], opw1p, 131072);
    pack3_bf16<<<dim3(320), blk, 0, stream>>>((const float*)d_in[32], ppw1p, 131072,
                                              (const float*)d_in[36], skw1p, 131072,
                                              (const float*)d_in[40], ndw1p, 65536);
    // op: (B,N,64) at offset 0
    gemm_nt_mfma<1><<<dim3(2, 32), blk, 0, stream>>>(out1p, opw1p, (const float*)d_in[29], bufA, 512, 256);
    gemm_nt<0><<<dim3(1, MR / 64), blk, 0, stream>>>(bufA, (const float*)d_in[30], (const float*)d_in[31], out, MR, 256, 64);
    // pp: (B,N,16) at offset 262144
    gemm_nt_mfma<1><<<dim3(2, 32), blk, 0, stream>>>(out1p, ppw1p, (const float*)d_in[33], bufA, 512, 256);
    gemm_nt<0><<<dim3(1, MR / 64), blk, 0, stream>>>(bufA, (const float*)d_in[34], (const float*)d_in[35], out + 262144, MR, 256, 16);
    // sk: (B,N,128) at offset 327680
    gemm_nt_mfma<1><<<dim3(2, 32), blk, 0, stream>>>(out1p, skw1p, (const float*)d_in[37], bufA, 512, 256);
    gemm_nt<0><<<dim3(2, MR / 64), blk, 0, stream>>>(bufA, (const float*)d_in[38], (const float*)d_in[39], out + 327680, MR, 256, 128);
    // nd: (B,N,128) at offset 851968 (input = GNN3 output)
    gemm_nt_mfma<1><<<dim3(2, 32), blk, 0, stream>>>(bufCp2, ndw1p, (const float*)d_in[41], bufA, 256, 256);
    gemm_nt<0><<<dim3(2, MR / 64), blk, 0, stream>>>(bufA, (const float*)d_in[42], (const float*)d_in[43], out + 851968, MR, 256, 128);
}

// Round 14
// 2363.252 us; speedup vs baseline: 1.7321x; 1.3537x over previous
//
#include <hip/hip_runtime.h>

// Problem constants (DeepCAD_1958505087412)
#define BB   8
#define NN   512      // nodes == timesteps
#define NDIM 128
#define HDIM 256      // GNN out dim == LSTM hidden
#define TT   512

__device__ __forceinline__ float sigmoidf_(float x) { return 1.0f / (1.0f + __expf(-x)); }
__device__ __forceinline__ float tanhf_(float x) { float e = __expf(2.0f * x); return 1.0f - 2.0f / (e + 1.0f); }

typedef _Float16 half2v __attribute__((ext_vector_type(2)));
typedef unsigned int uint4v __attribute__((ext_vector_type(4)));
typedef short bf16x8 __attribute__((ext_vector_type(8)));
typedef float f32x4 __attribute__((ext_vector_type(4)));
__device__ __forceinline__ float fdot2_(unsigned int w, unsigned int h, float acc) {
    return __builtin_amdgcn_fdot2(__builtin_bit_cast(half2v, w),
                                  __builtin_bit_cast(half2v, h), acc, false);
}
__device__ __forceinline__ unsigned short f2bf_(float x) {
    unsigned int u = __builtin_bit_cast(unsigned int, x);
    return (unsigned short)((u + 0x7FFFu + ((u >> 16) & 1u)) >> 16);   // RNE
}
__device__ __forceinline__ unsigned short f2h_(float x) {
    _Float16 h = (_Float16)x;
    return *(unsigned short*)&h;
}

// ---------------------------------------------------------------------------
// fp32 Y = X @ W^T + bias (optional ReLU) — small head layer-2 GEMMs.
// ---------------------------------------------------------------------------
template<int RELU>
__global__ __launch_bounds__(256) void gemm_nt(const float* __restrict__ X,
    const float* __restrict__ W, const float* __restrict__ bias,
    float* __restrict__ Y, int M, int K, int Nn)
{
    __shared__ float Xs[16][68];
    __shared__ float Ws[16][68];
    const int tid = threadIdx.x;
    const int m0 = blockIdx.y << 6;
    const int n0 = blockIdx.x << 6;
    const int lr = tid >> 2;
    const int lc = (tid & 3) << 2;
    const int tm = (tid >> 4) << 2;
    const int tn = (tid & 15) << 2;

    float acc[4][4] = {{0.f,0.f,0.f,0.f},{0.f,0.f,0.f,0.f},{0.f,0.f,0.f,0.f},{0.f,0.f,0.f,0.f}};

    const float* Xp = X + (size_t)(m0 + lr) * K + lc;
    const bool wok = (n0 + lr) < Nn;
    const float* Wp = wok ? (W + (size_t)(n0 + lr) * K + lc) : W;

    for (int k0 = 0; k0 < K; k0 += 16) {
        float4 xv = *(const float4*)(Xp + k0);
        float4 wv = *(const float4*)(Wp + k0);
        if (!wok) wv = make_float4(0.f, 0.f, 0.f, 0.f);
        __syncthreads();
        Xs[lc+0][lr]=xv.x; Xs[lc+1][lr]=xv.y; Xs[lc+2][lr]=xv.z; Xs[lc+3][lr]=xv.w;
        Ws[lc+0][lr]=wv.x; Ws[lc+1][lr]=wv.y; Ws[lc+2][lr]=wv.z; Ws[lc+3][lr]=wv.w;
        __syncthreads();
        #pragma unroll
        for (int kk = 0; kk < 16; ++kk) {
            const float4 a = *(const float4*)(&Xs[kk][tm]);
            const float4 b = *(const float4*)(&Ws[kk][tn]);
            acc[0][0] += a.x*b.x; acc[0][1] += a.x*b.y; acc[0][2] += a.x*b.z; acc[0][3] += a.x*b.w;
            acc[1][0] += a.y*b.x; acc[1][1] += a.y*b.y; acc[1][2] += a.y*b.z; acc[1][3] += a.y*b.w;
            acc[2][0] += a.z*b.x; acc[2][1] += a.z*b.y; acc[2][2] += a.z*b.z; acc[2][3] += a.z*b.w;
            acc[3][0] += a.w*b.x; acc[3][1] += a.w*b.y; acc[3][2] += a.w*b.z; acc[3][3] += a.w*b.w;
        }
    }
    const int nc = n0 + tn;
    if (nc >= Nn) return;
    float4 bv = make_float4(0.f, 0.f, 0.f, 0.f);
    if (bias) bv = *(const float4*)(bias + nc);
    #pragma unroll
    for (int i = 0; i < 4; ++i) {
        float4 o;
        o.x = acc[i][0] + bv.x; o.y = acc[i][1] + bv.y;
        o.z = acc[i][2] + bv.z; o.w = acc[i][3] + bv.w;
        if (RELU) { o.x=fmaxf(o.x,0.f); o.y=fmaxf(o.y,0.f); o.z=fmaxf(o.z,0.f); o.w=fmaxf(o.w,0.f); }
        *(float4*)(Y + (size_t)(m0 + tm + i) * Nn + nc) = o;
    }
}

// ---------------------------------------------------------------------------
// bf16 MFMA Y = X @ W^T + bias (optional ReLU). Verified r10/r11.
// ---------------------------------------------------------------------------
template<int RELU>
__global__ __launch_bounds__(256) void gemm_nt_mfma(
    const unsigned short* __restrict__ X, const unsigned short* __restrict__ W,
    const float* __restrict__ bias, float* __restrict__ Y, int K, int Nn)
{
    __shared__ unsigned short As[128][56];
    __shared__ unsigned short Bs[128][56];
    const int tid = threadIdx.x;
    const int m0 = blockIdx.y << 7;
    const int n0 = blockIdx.x << 7;
    const int wid = tid >> 6, lane = tid & 63;
    const int wm = (wid >> 1) << 6;
    const int wn = (wid & 1) << 6;
    const int sr = tid >> 2;
    const int sc = (tid & 3) << 3;

    f32x4 acc[4][4] = {};

    const int fr = lane & 15;
    const int kg = (lane >> 4) << 3;

    for (int k0 = 0; k0 < K; k0 += 32) {
        uint4 a0 = *(const uint4*)(X + (size_t)(m0 + sr) * K + k0 + sc);
        uint4 a1 = *(const uint4*)(X + (size_t)(m0 + sr + 64) * K + k0 + sc);
        uint4 b0 = *(const uint4*)(W + (size_t)(n0 + sr) * K + k0 + sc);
        uint4 b1 = *(const uint4*)(W + (size_t)(n0 + sr + 64) * K + k0 + sc);
        __syncthreads();
        *(uint4*)&As[sr][sc] = a0; *(uint4*)&As[sr + 64][sc] = a1;
        *(uint4*)&Bs[sr][sc] = b0; *(uint4*)&Bs[sr + 64][sc] = b1;
        __syncthreads();
        bf16x8 af[4], bf[4];
        #pragma unroll
        for (int i = 0; i < 4; ++i) {
            af[i] = *(const bf16x8*)&As[wm + i * 16 + fr][kg];
            bf[i] = *(const bf16x8*)&Bs[wn + i * 16 + fr][kg];
        }
        #pragma unroll
        for (int i = 0; i < 4; ++i)
            #pragma unroll
            for (int j = 0; j < 4; ++j)
                acc[i][j] = __builtin_amdgcn_mfma_f32_16x16x32_bf16(af[i], bf[j], acc[i][j], 0, 0, 0);
    }

    const int cr = (lane >> 4) << 2;
    const int cc = lane & 15;
    #pragma unroll
    for (int i = 0; i < 4; ++i) {
        #pragma unroll
        for (int j = 0; j < 4; ++j) {
            const int col = n0 + wn + j * 16 + cc;
            const float bv = bias ? bias[col] : 0.f;
            #pragma unroll
            for (int r = 0; r < 4; ++r) {
                const int row = m0 + wm + i * 16 + cr + r;
                float v = acc[i][j][r] + bv;
                if (RELU) v = fmaxf(v, 0.f);
                Y[(size_t)row * Nn + col] = v;
            }
        }
    }
}

// ---------------------------------------------------------------------------
// Batched Y[b] = (A[b] @ H[b]) * mask[b,:,None], optional ReLU (fp32).
// ---------------------------------------------------------------------------
template<int RELU>
__global__ __launch_bounds__(256) void gemm_nn_mask(const float* __restrict__ A,
    const float* __restrict__ Hm, const float* __restrict__ mask,
    float* __restrict__ Y, int M, int K, int Nn)
{
    const int b = blockIdx.z;
    A  += (size_t)b * M * K;
    Hm += (size_t)b * K * Nn;
    Y  += (size_t)b * M * Nn;
    __shared__ float As[16][68];
    __shared__ float Hs[16][68];
    const int tid = threadIdx.x;
    const int m0 = blockIdx.y << 6;
    const int n0 = blockIdx.x << 6;
    const int lr = tid >> 2;
    const int lc = (tid & 3) << 2;
    const int hr = tid >> 4;
    const int hc = (tid & 15) << 2;
    const int tm = (tid >> 4) << 2;
    const int tn = (tid & 15) << 2;

    float acc[4][4] = {{0.f,0.f,0.f,0.f},{0.f,0.f,0.f,0.f},{0.f,0.f,0.f,0.f},{0.f,0.f,0.f,0.f}};

    for (int k0 = 0; k0 < K; k0 += 16) {
        float4 av = *(const float4*)(A + (size_t)(m0 + lr) * K + k0 + lc);
        float4 hv = *(const float4*)(Hm + (size_t)(k0 + hr) * Nn + n0 + hc);
        __syncthreads();
        As[lc+0][lr]=av.x; As[lc+1][lr]=av.y; As[lc+2][lr]=av.z; As[lc+3][lr]=av.w;
        *(float4*)(&Hs[hr][hc]) = hv;
        __syncthreads();
        #pragma unroll
        for (int kk = 0; kk < 16; ++kk) {
            const float4 a = *(const float4*)(&As[kk][tm]);
            const float4 h = *(const float4*)(&Hs[kk][tn]);
            acc[0][0] += a.x*h.x; acc[0][1] += a.x*h.y; acc[0][2] += a.x*h.z; acc[0][3] += a.x*h.w;
            acc[1][0] += a.y*h.x; acc[1][1] += a.y*h.y; acc[1][2] += a.y*h.z; acc[1][3] += a.y*h.w;
            acc[2][0] += a.z*h.x; acc[2][1] += a.z*h.y; acc[2][2] += a.z*h.z; acc[2][3] += a.z*h.w;
            acc[3][0] += a.w*h.x; acc[3][1] += a.w*h.y; acc[3][2] += a.w*h.z; acc[3][3] += a.w*h.w;
        }
    }
    #pragma unroll
    for (int i = 0; i < 4; ++i) {
        const float mk = mask[b * M + m0 + tm + i];
        float4 o;
        o.x = acc[i][0]*mk; o.y = acc[i][1]*mk; o.z = acc[i][2]*mk; o.w = acc[i][3]*mk;
        if (RELU) { o.x=fmaxf(o.x,0.f); o.y=fmaxf(o.y,0.f); o.z=fmaxf(o.z,0.f); o.w=fmaxf(o.w,0.f); }
        *(float4*)(Y + (size_t)(m0 + tm + i) * Nn + n0 + tn) = o;
    }
}

// ---------------------------------------------------------------------------
__global__ __launch_bounds__(256) void attn_sisj(const float* __restrict__ h,
    const float* __restrict__ aw, const float* __restrict__ ab,
    float* __restrict__ si, float* __restrict__ sj)
{
    const int lane = threadIdx.x & 63;
    const int row  = (blockIdx.x << 2) + (threadIdx.x >> 6);
    const float4 hv = ((const float4*)(h + (size_t)row * HDIM))[lane];
    const float4 a1 = ((const float4*)aw)[lane];
    const float4 a2 = ((const float4*)(aw + HDIM))[lane];
    float s1 = hv.x*a1.x + hv.y*a1.y + hv.z*a1.z + hv.w*a1.w;
    float s2 = hv.x*a2.x + hv.y*a2.y + hv.z*a2.z + hv.w*a2.w;
    #pragma unroll
    for (int off = 32; off > 0; off >>= 1) {
        s1 += __shfl_down(s1, off);
        s2 += __shfl_down(s2, off);
    }
    if (lane == 0) { si[row] = s1 + ab[0]; sj[row] = s2; }
}

// ---------------------------------------------------------------------------
__global__ __launch_bounds__(512) void attn_score(const float* __restrict__ si,
    const float* __restrict__ sj, const float* __restrict__ adj,
    const float* __restrict__ mask, float* __restrict__ watt)
{
    const int bi = blockIdx.x;
    const int b  = bi >> 9;
    const int j  = threadIdx.x;
    const float s0 = si[bi];
    const float mi = mask[bi];
    float s = sigmoidf_(s0 + sj[(b << 9) + j]) * adj[(size_t)bi * NN + j] * mi * mask[(b << 9) + j];
    float t = s;
    #pragma unroll
    for (int off = 32; off > 0; off >>= 1) t += __shfl_down(t, off);
    __shared__ float red[8];
    const int lane = j & 63, wv = j >> 6;
    if (lane == 0) red[wv] = t;
    __syncthreads();
    if (j == 0) {
        float tot = 0.f;
        #pragma unroll
        for (int w = 0; w < 8; ++w) tot += red[w];
        red[0] = 1.0f / (tot + 1e-8f);
    }
    __syncthreads();
    watt[(size_t)bi * NN + j] = s * red[0];
}

// ---------------------------------------------------------------------------
// Pack 4 equal-size fp32 arrays -> f16x2 (u32). n = pairs per array (131072).
// Fuses the 4 scan-weight pack launches into one.
// ---------------------------------------------------------------------------
__global__ __launch_bounds__(256) void pack_f16x4(
    const float* __restrict__ s0, const float* __restrict__ s1,
    const float* __restrict__ s2, const float* __restrict__ s3,
    unsigned int* __restrict__ d0, unsigned int* __restrict__ d1,
    unsigned int* __restrict__ d2, unsigned int* __restrict__ d3, int n)
{
    int i = blockIdx.x * 256 + threadIdx.x;
    const int seg = i / n;
    const int l = i - seg * n;
    if (seg >= 4) return;
    const float* s = seg == 0 ? s0 : seg == 1 ? s1 : seg == 2 ? s2 : s3;
    unsigned int* d = seg == 0 ? d0 : seg == 1 ? d1 : seg == 2 ? d2 : d3;
    float2 v = ((const float2*)s)[l];
    d[l] = (unsigned int)f2h_(v.x) | ((unsigned int)f2h_(v.y) << 16);
}

// ---------------------------------------------------------------------------
__global__ __launch_bounds__(256) void pack3_bf16(
    const float* __restrict__ s0, unsigned short* __restrict__ d0, int n0,
    const float* __restrict__ s1, unsigned short* __restrict__ d1, int n1,
    const float* __restrict__ s2, unsigned short* __restrict__ d2, int n2)
{
    int i = (blockIdx.x * 256 + threadIdx.x) * 4;
    const float* s; unsigned short* d; int l;
    if (i < n0) { s = s0; d = d0; l = i; }
    else if (i < n0 + n1) { s = s1; d = d1; l = i - n0; }
    else if (i < n0 + n1 + n2) { s = s2; d = d2; l = i - n0 - n1; }
    else return;
    float4 v = *(const float4*)(s + l);
    ushort4 o;
    o.x = f2bf_(v.x); o.y = f2bf_(v.y); o.z = f2bf_(v.z); o.w = f2bf_(v.w);
    *(ushort4*)(d + l) = o;
}

// ---------------------------------------------------------------------------
// Single-block-per-chain LSTM scan (r9/r11 config, FINAL — 985-995 us/dispatch
// = structural floor: f16 weights (512 KB/chain) equal the ENTIRE per-CU
// register file, so full residency is impossible; cross-CU splits cost
// >=1.5 us/step in agent-scope sync (measured r2/r4/r12); AGPR staging adds
// copies on top of the stream (r8/r13). 1.92 us/step = 384 KB/step L2 stream
// (~1.25 us at ~300 GB/s per-CU return path) overlapped with VALU+barriers.)
// ---------------------------------------------------------------------------
__global__ __launch_bounds__(1024) __attribute__((amdgpu_waves_per_eu(4, 4)))
void lstm_scan7(
    const float* __restrict__ pre_f, const float* __restrict__ pre_b,
    const unsigned int* __restrict__ w16_f, const unsigned int* __restrict__ w16_b,
    float* __restrict__ out)
{
    __shared__ uint4v lw4[8 * 1024];
    __shared__ float g_s[1024];
    __shared__ unsigned int h2[128];

    const int chain = blockIdx.x;
    const int batch = chain >> 1;
    const int dir   = chain & 1;
    const float* pre = dir ? pre_b : pre_f;
    const unsigned int* w = dir ? w16_b : w16_f;
    const int t0 = threadIdx.x;

    const uint4v* wr = (const uint4v*)(w + (size_t)t0 * 128);

    #pragma unroll
    for (int i = 0; i < 8; ++i) lw4[i * 1024 + t0] = wr[24 + i];

#define WD(i) uint4v W##i = wr[i];
    WD(0) WD(1) WD(2) WD(3) WD(4) WD(5) WD(6) WD(7) WD(8) WD(9) WD(10) WD(11)
    WD(12) WD(13) WD(14) WD(15) WD(16) WD(17) WD(18) WD(19) WD(20) WD(21) WD(22) WD(23)
#undef WD
#define PIN_ALL \
    { \
        asm volatile("" : "+v"(W0)); asm volatile("" : "+v"(W1)); \
        asm volatile("" : "+v"(W2)); asm volatile("" : "+v"(W3)); \
        asm volatile("" : "+v"(W4)); asm volatile("" : "+v"(W5)); \
        asm volatile("" : "+v"(W6)); asm volatile("" : "+v"(W7)); \
        asm volatile("" : "+v"(W8)); asm volatile("" : "+v"(W9)); \
        asm volatile("" : "+v"(W10)); asm volatile("" : "+v"(W11)); \
        asm volatile("" : "+v"(W12)); asm volatile("" : "+v"(W13)); \
        asm volatile("" : "+v"(W14)); asm volatile("" : "+v"(W15)); \
        asm volatile("" : "+v"(W16)); asm volatile("" : "+v"(W17)); \
        asm volatile("" : "+v"(W18)); asm volatile("" : "+v"(W19)); \
        asm volatile("" : "+v"(W20)); asm volatile("" : "+v"(W21)); \
        asm volatile("" : "+v"(W22)); asm volatile("" : "+v"(W23)); \
    }
    PIN_ALL

    if (t0 < 128) h2[t0] = 0u;
    float c = 0.f;

    const int tt0 = dir ? (TT - 1) : 0;
    const long pstep = dir ? -1024 : 1024;
    const long ostep = dir ? -512 : 512;
    const float* pp = pre + ((size_t)batch * TT + tt0) * 1024 + t0;
    float* op = out + ((size_t)batch * TT + tt0) * 512 + dir * 256 + t0;
    float pv = *pp; pp += pstep;
    __syncthreads();

    for (int t = 0; t < TT; ++t) {
        PIN_ALL

        float pv_n = 0.f;
        if (t + 1 < TT) pv_n = *pp;
        pp += pstep;

        float a0 = 0.f, a1 = 0.f, a2 = 0.f, a3 = 0.f;
        const uint4v* h4 = (const uint4v*)h2;
#define DOT(i) { const uint4v hv = h4[i]; \
        a0 = fdot2_(W##i.x, hv.x, a0); a1 = fdot2_(W##i.y, hv.y, a1); \
        a2 = fdot2_(W##i.z, hv.z, a2); a3 = fdot2_(W##i.w, hv.w, a3); }
        DOT(0) DOT(1) DOT(2) DOT(3) DOT(4) DOT(5) DOT(6) DOT(7)
        DOT(8) DOT(9) DOT(10) DOT(11) DOT(12) DOT(13) DOT(14) DOT(15)
        DOT(16) DOT(17) DOT(18) DOT(19) DOT(20) DOT(21) DOT(22) DOT(23)
#undef DOT
        #pragma unroll
        for (int i = 0; i < 8; ++i) {
            const uint4v wv = lw4[i * 1024 + t0];
            const uint4v hv = h4[24 + i];
            a0 = fdot2_(wv.x, hv.x, a0); a1 = fdot2_(wv.y, hv.y, a1);
            a2 = fdot2_(wv.z, hv.z, a2); a3 = fdot2_(wv.w, hv.w, a3);
        }
        g_s[t0] = (a0 + a1) + (a2 + a3) + pv;
        __syncthreads();
        if (t0 < 256) {
            const float ig = sigmoidf_(g_s[t0]);
            const float fg = sigmoidf_(g_s[256 + t0]);
            const float gg = tanhf_(g_s[512 + t0]);
            const float og = sigmoidf_(g_s[768 + t0]);
            c = fg * c + ig * gg;
            const float h = og * tanhf_(c);
            *op = h;
            op += ostep;
            ((unsigned short*)h2)[t0] = f2h_(h);
        }
        pv = pv_n;
        __syncthreads();
    }
#undef PIN_ALL
}

// ---------------------------------------------------------------------------

extern "C" void kernel_launch(void* const* d_in, const int* in_sizes, int n_in,
                              void* d_out, int out_size, void* d_ws, size_t ws_size,
                              hipStream_t stream)
{
    const float* nf   = (const float*)d_in[0];
    const float* adj  = (const float*)d_in[1];
    const float* mask = (const float*)d_in[2];
    const float* g_w[3]  = {(const float*)d_in[4],  (const float*)d_in[8],  (const float*)d_in[12]};
    const float* g_b[3]  = {(const float*)d_in[5],  (const float*)d_in[9],  (const float*)d_in[13]};
    const float* g_aw[3] = {(const float*)d_in[6],  (const float*)d_in[10], (const float*)d_in[14]};
    const float* g_ab[3] = {(const float*)d_in[7],  (const float*)d_in[11], (const float*)d_in[15]};
    const float* wih0f = (const float*)d_in[16]; const float* whh0f = (const float*)d_in[17]; const float* b0f = (const float*)d_in[18];
    const float* wih0b = (const float*)d_in[19]; const float* whh0b = (const float*)d_in[20]; const float* b0b = (const float*)d_in[21];
    const float* wih1f = (const float*)d_in[22]; const float* whh1f = (const float*)d_in[23]; const float* b1f = (const float*)d_in[24];
    const float* wih1b = (const float*)d_in[25]; const float* whh1b = (const float*)d_in[26]; const float* b1b = (const float*)d_in[27];

    float* ws = (float*)d_ws;
    // Workspace layout (floats); total ~15.7M floats = ~63 MB (unchanged).
    float* bufA = ws;                       // (4096,256)
    float* bufB = bufA + 1048576;           // (4096,256); later f16 scan weights
    float* bufC = bufB + 1048576;           // (4096,256) GNN3 output
    float* si   = bufC + 1048576;           // (4096)
    float* sj   = si + 4096;                // (4096)
    float* out0 = sj + 4096;                // (4096,512)
    float* out1 = out0 + 2097152;           // (4096,512)
    float* P0   = out1 + 2097152;           // (4096,1024)
    float* P1   = P0 + 4194304;             // (4096,1024)
    float* watt = P0;                       // alias (GNN phase only)
    // f16 scan weights in bufB (dead after GNN3):
    unsigned int* w16_0f = (unsigned int*)bufB;
    unsigned int* w16_0b = w16_0f + 131072;
    unsigned int* w16_1f = w16_0b + 131072;
    unsigned int* w16_1b = w16_1f + 131072;
    // bf16 scratch, aliased into phase-dead regions:
    unsigned short* nfp   = (unsigned short*)P1;                 // 524288 e
    unsigned short* bufBp = (unsigned short*)(P1 + 262144);      // 1048576 e
    unsigned short* gwp1  = (unsigned short*)(P1 + 786432);      // 32768 e
    unsigned short* gwp2  = (unsigned short*)(P1 + 802816);      // 65536 e
    unsigned short* gwp3  = (unsigned short*)(P1 + 835584);      // 65536 e
    unsigned short* bufCp  = (unsigned short*)bufA;              // 1048576 e
    unsigned short* out0p  = (unsigned short*)bufA;              // 2097152 e
    unsigned short* wih0fp = (unsigned short*)out1;              // 262144 e
    unsigned short* wih0bp = (unsigned short*)(out1 + 131072);   // 262144 e
    unsigned short* wih1fp = (unsigned short*)(out1 + 262144);   // 524288 e
    unsigned short* wih1bp = (unsigned short*)(out1 + 524288);   // 524288 e
    unsigned short* out1p  = (unsigned short*)P0;                // 2097152 e
    unsigned short* bufCp2 = (unsigned short*)(P0 + 1048576);    // 1048576 e
    unsigned short* opw1p  = (unsigned short*)(P0 + 1572864);    // 131072 e
    unsigned short* ppw1p  = (unsigned short*)(P0 + 1638400);    // 131072 e
    unsigned short* skw1p  = (unsigned short*)(P0 + 1703936);    // 131072 e
    unsigned short* ndw1p  = (unsigned short*)(P0 + 1769472);    // 65536 e

    const int MR = BB * NN;                 // 4096 rows
    dim3 blk(256);

    // ---------------- GNN x3 (projections via MFMA) ----------------
    pack3_bf16<<<dim3(608), blk, 0, stream>>>(nf, nfp, 524288,
                                              g_w[0], gwp1, 32768,
                                              g_w[1], gwp2, 65536);
    auto run_attn = [&](int li, float* ob, bool relu) {
        attn_sisj<<<dim3(MR / 4), blk, 0, stream>>>(bufA, g_aw[li], g_ab[li], si, sj);
        attn_score<<<dim3(MR), dim3(512), 0, stream>>>(si, sj, adj, mask, watt);
        if (relu)
            gemm_nn_mask<1><<<dim3(HDIM / 64, NN / 64, BB), blk, 0, stream>>>(watt, bufA, mask, ob, NN, NN, HDIM);
        else
            gemm_nn_mask<0><<<dim3(HDIM / 64, NN / 64, BB), blk, 0, stream>>>(watt, bufA, mask, ob, NN, NN, HDIM);
    };
    gemm_nt_mfma<0><<<dim3(2, 32), blk, 0, stream>>>(nfp, gwp1, g_b[0], bufA, NDIM, HDIM);
    run_attn(0, bufB, true);
    pack3_bf16<<<dim3(1088), blk, 0, stream>>>(bufB, bufBp, 1048576,
                                               g_w[2], gwp3, 65536,
                                               (const float*)0, (unsigned short*)0, 0);
    gemm_nt_mfma<0><<<dim3(2, 32), blk, 0, stream>>>(bufBp, gwp2, g_b[1], bufA, HDIM, HDIM);
    run_attn(1, bufB, true);
    pack3_bf16<<<dim3(1024), blk, 0, stream>>>(bufB, bufBp, 1048576,
                                               (const float*)0, (unsigned short*)0, 0,
                                               (const float*)0, (unsigned short*)0, 0);
    gemm_nt_mfma<0><<<dim3(2, 32), blk, 0, stream>>>(bufBp, gwp3, g_b[2], bufA, HDIM, HDIM);
    run_attn(2, bufC, false);

    // ---------------- pack scan whh weights to f16 (bufB now dead) ----------
    pack_f16x4<<<dim3(2048), blk, 0, stream>>>(whh0f, whh0b, whh1f, whh1b,
                                               w16_0f, w16_0b, w16_1f, w16_1b, 131072);

    // ---------------- LSTM layer 0 ----------------
    pack3_bf16<<<dim3(1536), blk, 0, stream>>>(bufC, bufCp, 1048576,
                                               wih0f, wih0fp, 262144,
                                               wih0b, wih0bp, 262144);
    gemm_nt_mfma<0><<<dim3(8, 32), blk, 0, stream>>>(bufCp, wih0fp, b0f, P0, HDIM, 1024);
    gemm_nt_mfma<0><<<dim3(8, 32), blk, 0, stream>>>(bufCp, wih0bp, b0b, P1, HDIM, 1024);
    lstm_scan7<<<dim3(16), dim3(1024), 0, stream>>>(P0, P1, w16_0f, w16_0b, out0);

    // ---------------- LSTM layer 1 ----------------
    pack3_bf16<<<dim3(3072), blk, 0, stream>>>(out0, out0p, 2097152,
                                               wih1f, wih1fp, 524288,
                                               wih1b, wih1bp, 524288);
    gemm_nt_mfma<0><<<dim3(8, 32), blk, 0, stream>>>(out0p, wih1fp, b1f, P0, 512, 1024);
    gemm_nt_mfma<0><<<dim3(8, 32), blk, 0, stream>>>(out0p, wih1bp, b1b, P1, 512, 1024);
    lstm_scan7<<<dim3(16), dim3(1024), 0, stream>>>(P0, P1, w16_1f, w16_1b, out1);

    // ---------------- Heads ----------------
    float* out = (float*)d_out;
    pack3_bf16<<<dim3(3200), blk, 0, stream>>>(out1, out1p, 2097152,
                                               bufC, bufCp2, 1048576,
                                               (const float*)d_in[28], opw1p, 131072);
    pack3_bf16<<<dim3(320), blk, 0, stream>>>((const float*)d_in[32], ppw1p, 131072,
                                              (const float*)d_in[36], skw1p, 131072,
                                              (const float*)d_in[40], ndw1p, 65536);
    // op: (B,N,64) at offset 0
    gemm_nt_mfma<1><<<dim3(2, 32), blk, 0, stream>>>(out1p, opw1p, (const float*)d_in[29], bufA, 512, 256);
    gemm_nt<0><<<dim3(1, MR / 64), blk, 0, stream>>>(bufA, (const float*)d_in[30], (const float*)d_in[31], out, MR, 256, 64);
    // pp: (B,N,16) at offset 262144
    gemm_nt_mfma<1><<<dim3(2, 32), blk, 0, stream>>>(out1p, ppw1p, (const float*)d_in[33], bufA, 512, 256);
    gemm_nt<0><<<dim3(1, MR / 64), blk, 0, stream>>>(bufA, (const float*)d_in[34], (const float*)d_in[35], out + 262144, MR, 256, 16);
    // sk: (B,N,128) at offset 327680
    gemm_nt_mfma<1><<<dim3(2, 32), blk, 0, stream>>>(out1p, skw1p, (const float*)d_in[37], bufA, 512, 256);
    gemm_nt<0><<<dim3(2, MR / 64), blk, 0, stream>>>(bufA, (const float*)d_in[38], (const float*)d_in[39], out + 327680, MR, 256, 128);
    // nd: (B,N,128) at offset 851968 (input = GNN3 output)
    gemm_nt_mfma<1><<<dim3(2, 32), blk, 0, stream>>>(bufCp2, ndw1p, (const float*)d_in[41], bufA, 256, 256);
    gemm_nt<0><<<dim3(2, MR / 64), blk, 0, stream>>>(bufA, (const float*)d_in[42], (const float*)d_in[43], out + 851968, MR, 256, 128);
}